// Round 3
// baseline (625.897 us; speedup 1.0000x reference)
//
#include <hip/hip_runtime.h>
#include <math.h>

#define NN 512      // nodes
#define H 256       // hidden
#define NHEAD 8
#define DK 32
#define NLAYER 6

// ---------- block-wide reductions (256 threads, wave64) ----------
__device__ __forceinline__ float blk_sum(float v) {
  __shared__ float sb[4];
  #pragma unroll
  for (int o = 32; o; o >>= 1) v += __shfl_down(v, o, 64);
  if ((threadIdx.x & 63) == 0) sb[threadIdx.x >> 6] = v;
  __syncthreads();
  v = sb[0] + sb[1] + sb[2] + sb[3];
  __syncthreads();
  return v;
}

__device__ __forceinline__ float blk_max(float v) {
  __shared__ float sb[4];
  #pragma unroll
  for (int o = 32; o; o >>= 1) v = fmaxf(v, __shfl_down(v, o, 64));
  if ((threadIdx.x & 63) == 0) sb[threadIdx.x >> 6] = v;
  __syncthreads();
  v = fmaxf(fmaxf(sb[0], sb[1]), fmaxf(sb[2], sb[3]));
  __syncthreads();
  return v;
}

// ---------- precompute per-table-row projections ----------
// rows 0..31: edge_emb @ W_ee ; rows 32..159: edge_dist_emb @ W_ed
__global__ __launch_bounds__(256) void proj_kernel(
    const float* __restrict__ edge_emb, const float* __restrict__ edge_dist_emb,
    const float* __restrict__ W_ee, const float* __restrict__ W_ed,
    float* __restrict__ eeP, float* __restrict__ edP) {
  int r = blockIdx.x;
  const float* table; const float* W; float* out; int row;
  if (r < 32) { table = edge_emb;      W = W_ee; out = eeP; row = r; }
  else        { table = edge_dist_emb; W = W_ed; out = edP; row = r - 32; }
  int t = threadIdx.x;
  float val = table[row * H + t];
  float ss = blk_sum(val * val);
  float n = sqrtf(ss);
  float sc = (n > 1.f) ? 1.f / (n + 1e-7f) : 1.f;
  float v = val * sc;
  #pragma unroll
  for (int hh = 0; hh < NHEAD; hh++) {
    float p = blk_sum(v * W[t * NHEAD + hh]);
    if (t == 0) out[row * NHEAD + hh] = p;
  }
}

// ---------- build attn_bias [NH][N][N] ----------
__global__ __launch_bounds__(256) void bias_kernel(
    const int* __restrict__ ee, const int* __restrict__ ed,
    const float* __restrict__ eeP, const float* __restrict__ edP,
    const float* __restrict__ b_ee, const float* __restrict__ b_ed,
    float* __restrict__ bias) {
  __shared__ float seeP[32 * 8];
  __shared__ float sedP[128 * 8];
  __shared__ float sbe[8], sbd[8];
  int t = threadIdx.x;
  seeP[t] = eeP[t];                 // 256 elems
  #pragma unroll
  for (int i = 0; i < 4; i++) sedP[t + i * 256] = edP[t + i * 256];  // 1024
  if (t < 8) { sbe[t] = b_ee[t]; sbd[t] = b_ed[t]; }
  __syncthreads();
  int idx = blockIdx.x * 256 + t;   // flat (i*N + j), < 262144
  int e0 = ee[idx * 2], e1 = ee[idx * 2 + 1];
  int d = ed[idx];
  #pragma unroll
  for (int hh = 0; hh < NHEAD; hh++) {
    bias[hh * (NN * NN) + idx] =
        0.5f * (seeP[e0 * 8 + hh] + seeP[e1 * 8 + hh]) + sbe[hh]
        + sedP[d * 8 + hh] + sbd[hh];
  }
}

// ---------- generic 512x256x256 fp32 GEMM, fused epilogues ----------
// EPI 0: C = A@B + bias                    (plain, [M,256])
// EPI 1: head layout: C[((n>>5)*512+m)*32 + (n&31)] = (acc+bias)*scale
// EPI 2: C = resid + A@B + bias            (residual, [M,256])
// EPI 3: C = gelu_exact(A@B + bias)        ([M,256])
template<int EPI>
__global__ __launch_bounds__(256) void gemm256(
    const float* __restrict__ A, const float* __restrict__ B,
    const float* __restrict__ bias, const float* __restrict__ resid,
    float* __restrict__ C, float scale) {
  __shared__ float As[32][33], Bs[32][33];
  int bm = blockIdx.y * 32, bn = blockIdx.x * 32;
  int tid = threadIdx.x;
  int tx = tid & 15, ty = tid >> 4;
  float acc[2][2] = {};
  for (int k0 = 0; k0 < 256; k0 += 32) {
    #pragma unroll
    for (int i = 0; i < 4; i++) {
      int idx = tid + i * 256;
      int r = idx >> 5, c = idx & 31;
      As[r][c] = A[(bm + r) * 256 + k0 + c];
      Bs[r][c] = B[(k0 + r) * 256 + bn + c];
    }
    __syncthreads();
    #pragma unroll
    for (int k = 0; k < 32; k++) {
      float a0 = As[ty * 2][k],     a1 = As[ty * 2 + 1][k];
      float b0 = Bs[k][tx * 2],     b1 = Bs[k][tx * 2 + 1];
      acc[0][0] += a0 * b0; acc[0][1] += a0 * b1;
      acc[1][0] += a1 * b0; acc[1][1] += a1 * b1;
    }
    __syncthreads();
  }
  #pragma unroll
  for (int i = 0; i < 2; i++) {
    int m = bm + ty * 2 + i;
    #pragma unroll
    for (int j = 0; j < 2; j++) {
      int n = bn + tx * 2 + j;
      float v = acc[i][j] + bias[n];
      if (EPI == 0) {
        C[m * 256 + n] = v;
      } else if (EPI == 1) {
        C[(((n >> 5) * 512) + m) * 32 + (n & 31)] = v * scale;
      } else if (EPI == 2) {
        C[m * 256 + n] = resid[m * 256 + n] + v;
      } else {
        C[m * 256 + n] = 0.5f * v * (1.f + erff(v * 0.70710678118654752f));
      }
    }
  }
}

// ---------- scores = Q K^T + attn_bias ----------
__global__ __launch_bounds__(256) void qkt_kernel(
    const float* __restrict__ q, const float* __restrict__ k,
    const float* __restrict__ bias, float* __restrict__ P) {
  int hh = blockIdx.z;
  int i0 = blockIdx.y * 32, j0 = blockIdx.x * 32;
  const float* qh = q + hh * NN * DK;
  const float* kh = k + hh * NN * DK;
  __shared__ float Qs[32][33], Ks[32][33];
  int tid = threadIdx.x;
  #pragma unroll
  for (int i = 0; i < 4; i++) {
    int idx = tid + i * 256;
    int r = idx >> 5, c = idx & 31;
    Qs[r][c] = qh[(i0 + r) * DK + c];
    Ks[r][c] = kh[(j0 + r) * DK + c];
  }
  __syncthreads();
  int tx = tid & 15, ty = tid >> 4;
  float acc[2][2] = {};
  #pragma unroll
  for (int d = 0; d < DK; d++) {
    float q0 = Qs[ty * 2][d], q1 = Qs[ty * 2 + 1][d];
    float k0 = Ks[tx * 2][d], k1 = Ks[tx * 2 + 1][d];
    acc[0][0] += q0 * k0; acc[0][1] += q0 * k1;
    acc[1][0] += q1 * k0; acc[1][1] += q1 * k1;
  }
  #pragma unroll
  for (int i = 0; i < 2; i++) {
    #pragma unroll
    for (int j = 0; j < 2; j++) {
      int off = (hh * NN + i0 + ty * 2 + i) * NN + j0 + tx * 2 + j;
      P[off] = acc[i][j] + bias[off];
    }
  }
}

// ---------- row softmax over 512 cols ----------
__global__ __launch_bounds__(256) void softmax512(float* __restrict__ P) {
  float* row = P + (size_t)blockIdx.x * NN;
  int t = threadIdx.x;
  float a = row[t], b = row[t + 256];
  float m = blk_max(fmaxf(a, b));
  float ea = expf(a - m), eb = expf(b - m);
  float s = blk_sum(ea + eb);
  float inv = 1.f / s;
  row[t] = ea * inv;
  row[t + 256] = eb * inv;
}

// ---------- O = P @ V  (per head), write [N,H] layout ----------
__global__ __launch_bounds__(256) void pv_kernel(
    const float* __restrict__ P, const float* __restrict__ v,
    float* __restrict__ o) {
  int hh = blockIdx.y;
  int m0 = blockIdx.x * 32;
  const float* Ph = P + (size_t)hh * NN * NN;
  const float* vh = v + hh * NN * DK;
  __shared__ float Ps[32][33], Vs[32][33];
  int tid = threadIdx.x, tx = tid & 15, ty = tid >> 4;
  float acc[2][2] = {};
  for (int k0 = 0; k0 < NN; k0 += 32) {
    #pragma unroll
    for (int i = 0; i < 4; i++) {
      int idx = tid + i * 256;
      int r = idx >> 5, c = idx & 31;
      Ps[r][c] = Ph[(m0 + r) * NN + k0 + c];
      Vs[r][c] = vh[(k0 + r) * DK + c];
    }
    __syncthreads();
    #pragma unroll
    for (int k = 0; k < 32; k++) {
      float p0 = Ps[ty * 2][k], p1 = Ps[ty * 2 + 1][k];
      float v0 = Vs[k][tx * 2], v1 = Vs[k][tx * 2 + 1];
      acc[0][0] += p0 * v0; acc[0][1] += p0 * v1;
      acc[1][0] += p1 * v0; acc[1][1] += p1 * v1;
    }
    __syncthreads();
  }
  #pragma unroll
  for (int i = 0; i < 2; i++)
    #pragma unroll
    for (int j = 0; j < 2; j++)
      o[(m0 + ty * 2 + i) * H + hh * DK + tx * 2 + j] = acc[i][j];
}

// ---------- layernorm over H=256 ----------
__global__ __launch_bounds__(256) void ln_kernel(
    const float* __restrict__ x, const float* __restrict__ s,
    const float* __restrict__ b, float* __restrict__ y) {
  int row = blockIdx.x, t = threadIdx.x;
  float v = x[row * H + t];
  float mean = blk_sum(v) * (1.f / 256.f);
  float d = v - mean;
  float var = blk_sum(d * d) * (1.f / 256.f);
  y[row * H + t] = d * rsqrtf(var + 1e-5f) * s[t] + b[t];
}

extern "C" void kernel_launch(void* const* d_in, const int* in_sizes, int n_in,
                              void* d_out, int out_size, void* d_ws, size_t ws_size,
                              hipStream_t stream) {
  const float* x               = (const float*)d_in[0];
  const int*   edge_encodes    = (const int*)d_in[2];
  const int*   edge_dist_enc   = (const int*)d_in[3];
  const float* W_feat = (const float*)d_in[7];
  const float* b_feat = (const float*)d_in[8];
  const float* edge_emb      = (const float*)d_in[9];
  const float* edge_dist_emb = (const float*)d_in[10];
  const float* W_ee = (const float*)d_in[11];
  const float* b_ee = (const float*)d_in[12];
  const float* W_ed = (const float*)d_in[13];
  const float* b_ed = (const float*)d_in[14];
  const float* ln1_s = (const float*)d_in[15];
  const float* ln1_b = (const float*)d_in[16];
  const float* Wq = (const float*)d_in[17];
  const float* bq = (const float*)d_in[18];
  const float* Wk = (const float*)d_in[19];
  const float* bk = (const float*)d_in[20];
  const float* Wv = (const float*)d_in[21];
  const float* bv = (const float*)d_in[22];
  const float* Wo = (const float*)d_in[23];
  const float* bo = (const float*)d_in[24];
  const float* ln2_s = (const float*)d_in[25];
  const float* ln2_b = (const float*)d_in[26];
  const float* W1 = (const float*)d_in[27];
  const float* b1 = (const float*)d_in[28];
  const float* W2 = (const float*)d_in[29];
  const float* b2 = (const float*)d_in[30];

  float* h  = (float*)d_out;            // residual stream lives in d_out
  float* ws = (float*)d_ws;
  float* y    = ws;                     // 131072
  float* q    = y   + 131072;
  float* k    = q   + 131072;
  float* v    = k   + 131072;
  float* o    = v   + 131072;
  float* ffn  = o   + 131072;
  float* eeP  = ffn + 131072;           // 256
  float* edP  = eeP + 256;              // 1024
  float* bias = edP + 1024;             // 2097152 (8 MB)
  float* P    = bias + 2097152;         // 2097152 (8 MB)

  proj_kernel<<<160, 256, 0, stream>>>(edge_emb, edge_dist_emb, W_ee, W_ed, eeP, edP);
  bias_kernel<<<1024, 256, 0, stream>>>(edge_encodes, edge_dist_enc, eeP, edP, b_ee, b_ed, bias);

  dim3 gg(8, 16);  // (N/32, M/32)
  gemm256<0><<<gg, 256, 0, stream>>>(x, W_feat, b_feat, nullptr, h, 1.f);

  const float scale = 0.17677669529663687f;  // 1/sqrt(32)
  for (int l = 0; l < NLAYER; l++) {
    ln_kernel<<<512, 256, 0, stream>>>(h, ln1_s + l * H, ln1_b + l * H, y);
    gemm256<1><<<gg, 256, 0, stream>>>(y, Wq + l * H * H, bq + l * H, nullptr, q, scale);
    gemm256<1><<<gg, 256, 0, stream>>>(y, Wk + l * H * H, bk + l * H, nullptr, k, 1.f);
    gemm256<1><<<gg, 256, 0, stream>>>(y, Wv + l * H * H, bv + l * H, nullptr, v, 1.f);
    qkt_kernel<<<dim3(16, 16, 8), 256, 0, stream>>>(q, k, bias, P);
    softmax512<<<4096, 256, 0, stream>>>(P);
    pv_kernel<<<dim3(16, 8), 256, 0, stream>>>(P, v, o);
    gemm256<2><<<gg, 256, 0, stream>>>(o, Wo + l * H * H, bo + l * H, h, h, 1.f);
    ln_kernel<<<512, 256, 0, stream>>>(h, ln2_s + l * H, ln2_b + l * H, y);
    gemm256<3><<<gg, 256, 0, stream>>>(y, W1 + l * H * H, b1 + l * H, nullptr, ffn, 1.f);
    gemm256<2><<<gg, 256, 0, stream>>>(ffn, W2 + l * H * H, b2 + l * H, h, h, 1.f);
  }
}

// Round 4
// 312.972 us; speedup vs baseline: 1.9998x; 1.9998x over previous
//
#include <hip/hip_runtime.h>
#include <math.h>

#define NN 512
#define H 256
#define NHEAD 8
#define DK 32
#define NLAYER 6
#define QSCALE 0.17677669529663687f

typedef __attribute__((ext_vector_type(8))) short bf16x8;
typedef __attribute__((ext_vector_type(4))) short bf16x4;
typedef __attribute__((ext_vector_type(4))) float f32x4;

__device__ __forceinline__ short f2bf(float f) {
  union { float f; unsigned u; } v; v.f = f;
  unsigned r = (v.u + 0x7FFFu + ((v.u >> 16) & 1u)) >> 16;
  return (short)r;
}
__device__ __forceinline__ float bf2f(short s) {
  union { unsigned u; float f; } v; v.u = ((unsigned)(unsigned short)s) << 16;
  return v.f;
}

// ---------- block-wide reduction (256 threads) ----------
__device__ __forceinline__ float blk_sum(float v) {
  __shared__ float sb[4];
  #pragma unroll
  for (int o = 32; o; o >>= 1) v += __shfl_down(v, o, 64);
  if ((threadIdx.x & 63) == 0) sb[threadIdx.x >> 6] = v;
  __syncthreads();
  v = sb[0] + sb[1] + sb[2] + sb[3];
  __syncthreads();
  return v;
}

// ---------- per-table-row projections (rows 0..31 ee, 32..159 ed) ----------
__global__ __launch_bounds__(256) void proj_kernel(
    const float* __restrict__ edge_emb, const float* __restrict__ edge_dist_emb,
    const float* __restrict__ W_ee, const float* __restrict__ W_ed,
    float* __restrict__ eeP, float* __restrict__ edP) {
  int r = blockIdx.x;
  const float* table; const float* W; float* out; int row;
  if (r < 32) { table = edge_emb;      W = W_ee; out = eeP; row = r; }
  else        { table = edge_dist_emb; W = W_ed; out = edP; row = r - 32; }
  int t = threadIdx.x;
  float val = table[row * H + t];
  float ss = blk_sum(val * val);
  float n = sqrtf(ss);
  float sc = (n > 1.f) ? 1.f / (n + 1e-7f) : 1.f;
  float v = val * sc;
  #pragma unroll
  for (int hh = 0; hh < NHEAD; hh++) {
    float p = blk_sum(v * W[t * NHEAD + hh]);
    if (t == 0) out[row * NHEAD + hh] = p;
  }
}

// ---------- build attn_bias [NH][N][N] fp32 ----------
__global__ __launch_bounds__(256) void bias_kernel(
    const int* __restrict__ ee, const int* __restrict__ ed,
    const float* __restrict__ eeP, const float* __restrict__ edP,
    const float* __restrict__ b_ee, const float* __restrict__ b_ed,
    float* __restrict__ bias) {
  __shared__ float seeP[32 * 8];
  __shared__ float sedP[128 * 8];
  __shared__ float sbe[8], sbd[8];
  int t = threadIdx.x;
  seeP[t] = eeP[t];
  #pragma unroll
  for (int i = 0; i < 4; i++) sedP[t + i * 256] = edP[t + i * 256];
  if (t < 8) { sbe[t] = b_ee[t]; sbd[t] = b_ed[t]; }
  __syncthreads();
  int idx = blockIdx.x * 256 + t;
  int e0 = ee[idx * 2], e1 = ee[idx * 2 + 1];
  int d = ed[idx];
  #pragma unroll
  for (int hh = 0; hh < NHEAD; hh++) {
    bias[hh * (NN * NN) + idx] =
        0.5f * (seeP[e0 * 8 + hh] + seeP[e1 * 8 + hh]) + sbe[hh]
        + sedP[d * 8 + hh] + sbd[hh];
  }
}

// ---------- transpose+cast all weights to bf16 WT[n][k] ----------
// blocks 0..2303: per-layer mats {Wq(scale),Wk,Wv,Wo,W1,W2}; 2304..2367: W_feat
__global__ __launch_bounds__(256) void wcast_kernel(
    const float* __restrict__ Wq, const float* __restrict__ Wk,
    const float* __restrict__ Wv, const float* __restrict__ Wo,
    const float* __restrict__ W1, const float* __restrict__ W2,
    const float* __restrict__ Wf,
    short* __restrict__ AqkT, short* __restrict__ AvT, short* __restrict__ AoT,
    short* __restrict__ A1T, short* __restrict__ A2T, short* __restrict__ WfT) {
  __shared__ float tile[32][33];
  int b = blockIdx.x;
  const float* src; short* dst; float scl = 1.f;
  int t;
  if (b < 2304) {
    int l = b / 384; int rr = b % 384; int mat = rr / 64; t = rr % 64;
    if      (mat == 0) { src = Wq + l * 65536; dst = AqkT + l * 131072; scl = QSCALE; }
    else if (mat == 1) { src = Wk + l * 65536; dst = AqkT + l * 131072 + 65536; }
    else if (mat == 2) { src = Wv + l * 65536; dst = AvT + l * 65536; }
    else if (mat == 3) { src = Wo + l * 65536; dst = AoT + l * 65536; }
    else if (mat == 4) { src = W1 + l * 65536; dst = A1T + l * 65536; }
    else               { src = W2 + l * 65536; dst = A2T + l * 65536; }
  } else {
    src = Wf; dst = WfT; t = b - 2304;
  }
  int tr = t >> 3, tc = t & 7;      // k-tile, n-tile
  int tid = threadIdx.x;
  int kl = tid >> 3, nl4 = (tid & 7) * 4;
  float4 v = *(const float4*)(src + (tr * 32 + kl) * 256 + tc * 32 + nl4);
  tile[kl][nl4 + 0] = v.x; tile[kl][nl4 + 1] = v.y;
  tile[kl][nl4 + 2] = v.z; tile[kl][nl4 + 3] = v.w;
  __syncthreads();
  int nl = tid >> 3, kl4 = (tid & 7) * 4;
  bf16x4 o;
  #pragma unroll
  for (int i = 0; i < 4; i++) o[i] = f2bf(tile[kl4 + i][nl] * scl);
  *(bf16x4*)(dst + (tc * 32 + nl) * 256 + tr * 32 + kl4) = o;
}

// ---------- layernorm: h fp32 -> y bf16 ----------
__global__ __launch_bounds__(256) void ln_kernel(
    const float* __restrict__ x, const float* __restrict__ s,
    const float* __restrict__ b, short* __restrict__ y) {
  int row = blockIdx.x, t = threadIdx.x;
  float v = x[row * H + t];
  float mean = blk_sum(v) * (1.f / 256.f);
  float d = v - mean;
  float var = blk_sum(d * d) * (1.f / 256.f);
  y[row * H + t] = f2bf(d * rsqrtf(var + 1e-5f) * s[t] + b[t]);
}

// ---------- MFMA GEMM: C[M][N] = A[M][K=256] @ Bt[N][K=256]^T ----------
// EPI 0: FEAT  A fp32; C1 fp32 = acc + bias[n]
// EPI 1: QK    C-> q_bf (n<256, bias*QSCALE) / k_bf (n>=256): [h][node][dk] bf16
// EPI 2: VT    C1 bf16 [m][512]: acc + bias[m]   (m = dk_global, n = node)
// EPI 3: RES   C1 fp32 = resid + acc + bias[n]
// EPI 4: GELU  C1 bf16 = gelu(acc + bias[n])
template<int EPI>
__global__ __launch_bounds__(256) void gemmT(
    const void* __restrict__ Av, const short* __restrict__ Bt,
    const float* __restrict__ bias, const float* __restrict__ bias2,
    const float* __restrict__ resid, void* __restrict__ C1, void* __restrict__ C2) {
  __shared__ short As[64 * 32], Bs[64 * 32];
  int tid = threadIdx.x;
  int w = tid >> 6, l = tid & 63;
  int bm = blockIdx.y * 64, bn = blockIdx.x * 64;
  int wm = (w >> 1) * 32, wn = (w & 1) * 32;
  f32x4 acc[2][2] = {};
  int srow = tid >> 2, sseg = tid & 3;
  for (int k0 = 0; k0 < 256; k0 += 32) {
    if (EPI == 0) {
      const float* A = (const float*)Av;
      const float4* pa = (const float4*)(A + (bm + srow) * 256 + k0 + sseg * 8);
      float4 a0 = pa[0], a1 = pa[1];
      bf16x8 va;
      va[0] = f2bf(a0.x); va[1] = f2bf(a0.y); va[2] = f2bf(a0.z); va[3] = f2bf(a0.w);
      va[4] = f2bf(a1.x); va[5] = f2bf(a1.y); va[6] = f2bf(a1.z); va[7] = f2bf(a1.w);
      *(bf16x8*)(As + srow * 32 + sseg * 8) = va;
    } else {
      const short* A = (const short*)Av;
      *(bf16x8*)(As + srow * 32 + sseg * 8) =
          *(const bf16x8*)(A + (bm + srow) * 256 + k0 + sseg * 8);
    }
    *(bf16x8*)(Bs + srow * 32 + sseg * 8) =
        *(const bf16x8*)(Bt + (bn + srow) * 256 + k0 + sseg * 8);
    __syncthreads();
    bf16x8 a0 = *(bf16x8*)(As + (wm + (l & 15)) * 32 + (l >> 4) * 8);
    bf16x8 a1 = *(bf16x8*)(As + (wm + 16 + (l & 15)) * 32 + (l >> 4) * 8);
    bf16x8 b0 = *(bf16x8*)(Bs + (wn + (l & 15)) * 32 + (l >> 4) * 8);
    bf16x8 b1 = *(bf16x8*)(Bs + (wn + 16 + (l & 15)) * 32 + (l >> 4) * 8);
    acc[0][0] = __builtin_amdgcn_mfma_f32_16x16x32_bf16(a0, b0, acc[0][0], 0, 0, 0);
    acc[0][1] = __builtin_amdgcn_mfma_f32_16x16x32_bf16(a0, b1, acc[0][1], 0, 0, 0);
    acc[1][0] = __builtin_amdgcn_mfma_f32_16x16x32_bf16(a1, b0, acc[1][0], 0, 0, 0);
    acc[1][1] = __builtin_amdgcn_mfma_f32_16x16x32_bf16(a1, b1, acc[1][1], 0, 0, 0);
    __syncthreads();
  }
  #pragma unroll
  for (int msub = 0; msub < 2; msub++) {
    #pragma unroll
    for (int nsub = 0; nsub < 2; nsub++) {
      f32x4 c = acc[msub][nsub];
      #pragma unroll
      for (int r = 0; r < 4; r++) {
        int m = bm + wm + msub * 16 + (l >> 4) * 4 + r;
        int n = bn + wn + nsub * 16 + (l & 15);
        float v = c[r];
        if (EPI == 0) {
          ((float*)C1)[m * 256 + n] = v + bias[n];
        } else if (EPI == 1) {
          if (n < 256) {
            float val = v + bias[n] * QSCALE;
            ((short*)C1)[(((n >> 5) * 512) + m) * 32 + (n & 31)] = f2bf(val);
          } else {
            int nn = n - 256;
            float val = v + bias2[nn];
            ((short*)C2)[(((nn >> 5) * 512) + m) * 32 + (nn & 31)] = f2bf(val);
          }
        } else if (EPI == 2) {
          ((short*)C1)[m * 512 + n] = f2bf(v + bias[m]);
        } else if (EPI == 3) {
          ((float*)C1)[m * 256 + n] = resid[m * 256 + n] + v + bias[n];
        } else {
          float val = v + bias[n];
          ((short*)C1)[m * 256 + n] = f2bf(0.5f * val * (1.f + erff(val * 0.70710678118654752f)));
        }
      }
    }
  }
}

// ---------- fused attention: per (qtile of 32 rows, head) ----------
// q_bf,k_bf: [h][node][dk] bf16 ; vT: [h*32+dk][node] bf16 ; bias fp32 [h][N][N]
#define SSTR 516
#define PSTR 520
__global__ __launch_bounds__(256) void attn_kernel(
    const short* __restrict__ qb, const short* __restrict__ kb,
    const short* __restrict__ vT, const float* __restrict__ bias,
    short* __restrict__ ob) {
  __shared__ float S[32 * SSTR];
  __shared__ short P[32 * PSTR];
  __shared__ short Kst[64 * 32];
  int h = blockIdx.y, m0 = blockIdx.x * 32;
  int tid = threadIdx.x, w = tid >> 6, l = tid & 63;

  const short* qrow = qb + (h * 512 + m0) * 32;
  bf16x8 aq0 = *(const bf16x8*)(qrow + (l & 15) * 32 + (l >> 4) * 8);
  bf16x8 aq1 = *(const bf16x8*)(qrow + (16 + (l & 15)) * 32 + (l >> 4) * 8);

  int snode = tid >> 2, sseg = tid & 3;
  for (int c = 0; c < 8; c++) {
    *(bf16x8*)(Kst + snode * 32 + sseg * 8) =
        *(const bf16x8*)(kb + (h * 512 + c * 64 + snode) * 32 + sseg * 8);
    __syncthreads();
    bf16x8 bk = *(const bf16x8*)(Kst + (w * 16 + (l & 15)) * 32 + (l >> 4) * 8);
    f32x4 s0 = {}, s1 = {};
    s0 = __builtin_amdgcn_mfma_f32_16x16x32_bf16(aq0, bk, s0, 0, 0, 0);
    s1 = __builtin_amdgcn_mfma_f32_16x16x32_bf16(aq1, bk, s1, 0, 0, 0);
    int node = c * 64 + w * 16 + (l & 15);
    #pragma unroll
    for (int r = 0; r < 4; r++) {
      int r0 = (l >> 4) * 4 + r;
      S[r0 * SSTR + node] = s0[r] + bias[(h * 512 + m0 + r0) * 512 + node];
      S[(16 + r0) * SSTR + node] = s1[r] + bias[(h * 512 + m0 + 16 + r0) * 512 + node];
    }
    __syncthreads();
  }

  // softmax: row r = tid>>3, 8 threads per row, stride-8 elements
  {
    int r = tid >> 3, j = tid & 7;
    float* Srow = S + r * SSTR;
    float mx = -1e30f;
    #pragma unroll 8
    for (int t = 0; t < 64; t++) mx = fmaxf(mx, Srow[j + t * 8]);
    #pragma unroll
    for (int o = 4; o; o >>= 1) mx = fmaxf(mx, __shfl_xor(mx, o, 8));
    float sum = 0.f;
    #pragma unroll 8
    for (int t = 0; t < 64; t++) sum += __expf(Srow[j + t * 8] - mx);
    #pragma unroll
    for (int o = 4; o; o >>= 1) sum += __shfl_xor(sum, o, 8);
    float inv = 1.f / sum;
    #pragma unroll 8
    for (int t = 0; t < 64; t++)
      P[r * PSTR + j + t * 8] = f2bf(__expf(Srow[j + t * 8] - mx) * inv);
  }
  __syncthreads();

  // PV: wave w -> C quadrant (msub = (w>>1)*16 q-rows, nsub = (w&1)*16 dks)
  int msub = (w >> 1) * 16, nsub = (w & 1) * 16;
  const short* vrow = vT + (h * 32 + nsub + (l & 15)) * 512;
  f32x4 oc = {};
  #pragma unroll
  for (int ch = 0; ch < 16; ch++) {
    bf16x8 ap = *(bf16x8*)(P + (msub + (l & 15)) * PSTR + ch * 32 + (l >> 4) * 8);
    bf16x8 bv = *(const bf16x8*)(vrow + ch * 32 + (l >> 4) * 8);
    oc = __builtin_amdgcn_mfma_f32_16x16x32_bf16(ap, bv, oc, 0, 0, 0);
  }
  #pragma unroll
  for (int r = 0; r < 4; r++)
    ob[(m0 + msub + (l >> 4) * 4 + r) * 256 + h * 32 + nsub + (l & 15)] = f2bf(oc[r]);
}

extern "C" void kernel_launch(void* const* d_in, const int* in_sizes, int n_in,
                              void* d_out, int out_size, void* d_ws, size_t ws_size,
                              hipStream_t stream) {
  const float* x             = (const float*)d_in[0];
  const int*   edge_encodes  = (const int*)d_in[2];
  const int*   edge_dist_enc = (const int*)d_in[3];
  const float* W_feat = (const float*)d_in[7];
  const float* b_feat = (const float*)d_in[8];
  const float* edge_emb      = (const float*)d_in[9];
  const float* edge_dist_emb = (const float*)d_in[10];
  const float* W_ee = (const float*)d_in[11];
  const float* b_ee = (const float*)d_in[12];
  const float* W_ed = (const float*)d_in[13];
  const float* b_ed = (const float*)d_in[14];
  const float* ln1_s = (const float*)d_in[15];
  const float* ln1_b = (const float*)d_in[16];
  const float* Wq = (const float*)d_in[17];
  const float* bq = (const float*)d_in[18];
  const float* Wk = (const float*)d_in[19];
  const float* bk = (const float*)d_in[20];
  const float* Wv = (const float*)d_in[21];
  const float* bv = (const float*)d_in[22];
  const float* Wo = (const float*)d_in[23];
  const float* bo = (const float*)d_in[24];
  const float* ln2_s = (const float*)d_in[25];
  const float* ln2_b = (const float*)d_in[26];
  const float* W1 = (const float*)d_in[27];
  const float* b1 = (const float*)d_in[28];
  const float* W2 = (const float*)d_in[29];
  const float* b2 = (const float*)d_in[30];

  float* h = (float*)d_out;
  char* base = (char*)d_ws;
  float* bias = (float*)base;                         // 8 MB
  short* AqkT = (short*)(base + 8388608);             // 1.5 MB
  short* AvT  = (short*)(base + 9961472);
  short* AoT  = (short*)(base + 10747904);
  short* A1T  = (short*)(base + 11534336);
  short* A2T  = (short*)(base + 12320768);
  short* WfT  = (short*)(base + 13107200);
  short* y_bf = (short*)(base + 13238272);
  short* q_bf = (short*)(base + 13500416);
  short* k_bf = (short*)(base + 13762560);
  short* vT_bf= (short*)(base + 14024704);
  short* o_bf = (short*)(base + 14286848);
  short* g_bf = (short*)(base + 14548992);
  float* eeP  = (float*)(base + 14811136);
  float* edP  = (float*)(base + 14812160);

  wcast_kernel<<<2368, 256, 0, stream>>>(Wq, Wk, Wv, Wo, W1, W2, W_feat,
                                         AqkT, AvT, AoT, A1T, A2T, WfT);
  proj_kernel<<<160, 256, 0, stream>>>(edge_emb, edge_dist_emb, W_ee, W_ed, eeP, edP);
  bias_kernel<<<1024, 256, 0, stream>>>(edge_encodes, edge_dist_enc, eeP, edP, b_ee, b_ed, bias);

  gemmT<0><<<dim3(4, 8), 256, 0, stream>>>(x, WfT, b_feat, nullptr, nullptr, h, nullptr);

  for (int l = 0; l < NLAYER; l++) {
    ln_kernel<<<512, 256, 0, stream>>>(h, ln1_s + l * H, ln1_b + l * H, y_bf);
    gemmT<1><<<dim3(8, 8), 256, 0, stream>>>(y_bf, AqkT + l * 131072,
                                             bq + l * H, bk + l * H, nullptr, q_bf, k_bf);
    gemmT<2><<<dim3(8, 4), 256, 0, stream>>>(AvT + l * 65536, y_bf,
                                             bv + l * H, nullptr, nullptr, vT_bf, nullptr);
    attn_kernel<<<dim3(16, 8), 256, 0, stream>>>(q_bf, k_bf, vT_bf, bias, o_bf);
    gemmT<3><<<dim3(4, 8), 256, 0, stream>>>(o_bf, AoT + l * 65536,
                                             bo + l * H, nullptr, h, h, nullptr);
    ln_kernel<<<512, 256, 0, stream>>>(h, ln2_s + l * H, ln2_b + l * H, y_bf);
    gemmT<4><<<dim3(4, 8), 256, 0, stream>>>(y_bf, A1T + l * 65536,
                                             b1 + l * H, nullptr, nullptr, g_bf, nullptr);
    gemmT<3><<<dim3(4, 8), 256, 0, stream>>>(g_bf, A2T + l * 65536,
                                             b2 + l * H, nullptr, h, h, nullptr);
  }
}